// Round 3
// baseline (177.105 us; speedup 1.0000x reference)
//
#include <hip/hip_runtime.h>
#include <hip/hip_bf16.h>

#define N_NODES 100000
#define N_EDGES 250000
#define EMB 32
#define TYPES 16

// ---------------------------------------------------------------------------
// Layer 1: per-edge msg = entity[src_ids[edge_src[e]]] @ W1[etype]  (32x32),
// scatter-add into s1[dst]. 32 lanes per edge; lane j owns output column j.
// deg computed here (same edge_dst used by layer 2).
__global__ void layer1_edges_kernel(const float* __restrict__ entity,
                                    const int* __restrict__ src_ids,
                                    const float* __restrict__ W1,
                                    const int* __restrict__ edge_src,
                                    const int* __restrict__ edge_dst,
                                    const int* __restrict__ etype,
                                    float* __restrict__ s1,
                                    float* __restrict__ deg) {
    int t = blockIdx.x * blockDim.x + threadIdx.x;
    int e = t >> 5;
    if (e >= N_EDGES) return;
    int j = t & 31;
    int s = edge_src[e];
    int d = edge_dst[e];
    int r = etype[e];
    int sid = src_ids[s];                             // double indirection (h = entity[src_ids])

    float hj = entity[sid * EMB + j];                 // lane j holds h[j]
    const float* w = W1 + (size_t)r * (EMB * EMB) + j;  // column j

    float acc = 0.f;
#pragma unroll
    for (int k = 0; k < EMB; ++k) {
        float hk = __shfl(hj, k, 32);                 // broadcast h[k] within edge group
        acc += hk * w[k * EMB];                       // W1[r][k][j], coalesced over j
    }
    atomicAdd(&s1[d * EMB + j], acc);
    if (j == 0) atomicAdd(&deg[d], 1.0f);
}

// ---------------------------------------------------------------------------
// h1 = relu(s1 / max(deg,1))   in place
__global__ void finalize1_kernel(float* __restrict__ s1,
                                 const float* __restrict__ deg) {
    int t = blockIdx.x * blockDim.x + threadIdx.x;    // over N_NODES*EMB
    if (t >= N_NODES * EMB) return;
    int n = t >> 5;
    float dv = fmaxf(deg[n], 1.0f);
    float v = s1[t] / dv;
    s1[t] = v > 0.f ? v : 0.f;
}

// ---------------------------------------------------------------------------
// Layer 2: per-edge msg = h1[src] @ W2[etype]  (32x16), scatter-add into s2[dst].
// 16 lanes per edge; lane j owns output column j; h row split across lanes (lo/hi 16).
__global__ void layer2_edges_kernel(const float* __restrict__ h1,
                                    const float* __restrict__ W2,
                                    const int* __restrict__ edge_src,
                                    const int* __restrict__ edge_dst,
                                    const int* __restrict__ etype,
                                    float* __restrict__ s2) {
    int t = blockIdx.x * blockDim.x + threadIdx.x;
    int e = t >> 4;
    if (e >= N_EDGES) return;
    int j = t & 15;
    int s = edge_src[e];
    int d = edge_dst[e];
    int r = etype[e];

    float hlo = h1[s * EMB + j];                      // h[j]
    float hhi = h1[s * EMB + 16 + j];                 // h[16+j]
    const float* w = W2 + (size_t)r * (EMB * TYPES) + j;

    float acc = 0.f;
#pragma unroll
    for (int k = 0; k < 16; ++k) {
        float hk = __shfl(hlo, k, 16);
        acc += hk * w[k * TYPES];
    }
#pragma unroll
    for (int k = 0; k < 16; ++k) {
        float hk = __shfl(hhi, k, 16);
        acc += hk * w[(16 + k) * TYPES];
    }
    atomicAdd(&s2[d * TYPES + j], acc);
}

// ---------------------------------------------------------------------------
// Head: h2 = s2/max(deg,1);  lam = sigmoid(h2 . lambda_w + lambda_b)
// out = [ y (=h2, twice, [2,N,16]) ; p ([lam, 1-lam], [2,N]) ]  all fp32
__global__ void head_kernel(const float* __restrict__ s2,
                            const float* __restrict__ deg,
                            const float* __restrict__ lw,
                            const float* __restrict__ lb,
                            float* __restrict__ out) {
    int n = blockIdx.x * blockDim.x + threadIdx.x;
    if (n >= N_NODES) return;
    float inv = 1.0f / fmaxf(deg[n], 1.0f);

    float h[TYPES];
    float dot = 0.f;
#pragma unroll
    for (int j = 0; j < TYPES; ++j) {
        h[j] = s2[n * TYPES + j] * inv;
        dot += h[j] * lw[j];
    }
    dot += lb[0];
    float lam = 1.0f / (1.0f + expf(-dot));

#pragma unroll
    for (int j = 0; j < TYPES; ++j) {
        float v = h[j];
        out[(size_t)n * TYPES + j] = v;                               // y[0]
        out[(size_t)N_NODES * TYPES + (size_t)n * TYPES + j] = v;     // y[1]
    }
    out[(size_t)2 * N_NODES * TYPES + n] = lam;                       // p[0]
    out[(size_t)2 * N_NODES * TYPES + N_NODES + n] = 1.0f - lam;      // p[1]
}

// ---------------------------------------------------------------------------
extern "C" void kernel_launch(void* const* d_in, const int* in_sizes, int n_in,
                              void* d_out, int out_size, void* d_ws, size_t ws_size,
                              hipStream_t stream) {
    const float* entity = (const float*)d_in[0];
    const float* W1     = (const float*)d_in[1];
    const float* W2     = (const float*)d_in[2];
    const float* lw     = (const float*)d_in[3];
    const float* lb     = (const float*)d_in[4];
    const int* src_ids  = (const int*)d_in[5];
    const int* edge_src = (const int*)d_in[6];
    const int* edge_dst = (const int*)d_in[7];
    const int* etype    = (const int*)d_in[8];
    float* out = (float*)d_out;

    // workspace layout (fp32): s1[32N] | s2[16N] | deg[N]  = 19.6 MB
    float* s1  = (float*)d_ws;
    float* s2  = s1 + (size_t)N_NODES * EMB;
    float* deg = s2 + (size_t)N_NODES * TYPES;
    size_t used_bytes = (size_t)N_NODES * (EMB + TYPES + 1) * sizeof(float);

    hipMemsetAsync(d_ws, 0, used_bytes, stream);      // ws re-poisoned every call

    const int B = 256;
    layer1_edges_kernel<<<((size_t)N_EDGES * 32 + B - 1) / B, B, 0, stream>>>(
        entity, src_ids, W1, edge_src, edge_dst, etype, s1, deg);
    finalize1_kernel<<<(N_NODES * EMB + B - 1) / B, B, 0, stream>>>(s1, deg);
    layer2_edges_kernel<<<((size_t)N_EDGES * 16 + B - 1) / B, B, 0, stream>>>(
        s1, W2, edge_src, edge_dst, etype, s2);
    head_kernel<<<(N_NODES + B - 1) / B, B, 0, stream>>>(s2, deg, lw, lb, out);
}